// Round 7
// baseline (224.065 us; speedup 1.0000x reference)
//
#include <hip/hip_runtime.h>
#include <math.h>

// Problem constants
constexpr int B   = 16;
constexpr int C   = 256;
constexpr int H   = 64;
constexpr int W   = 64;
constexpr int K   = 4;
constexpr int O   = 256;
constexpr int HID = 65;
constexpr float TEMP = 34.0f;

typedef __bf16 bf16x8 __attribute__((ext_vector_type(8)));
typedef float  f32x16 __attribute__((ext_vector_type(16)));
typedef unsigned short ushort_t;

__device__ inline ushort_t f2bf(float f) {
    union { float f; unsigned u; } v; v.f = f;
    unsigned u = v.u;
    u += 0x7FFF + ((u >> 16) & 1);       // RNE
    return (ushort_t)(u >> 16);
}

__device__ inline void gl2lds16(const void* g, void* l) {
    __builtin_amdgcn_global_load_lds(
        (const __attribute__((address_space(1))) unsigned int*)g,
        (__attribute__((address_space(3))) unsigned int*)l, 16, 0, 0);
}

// ---------------------------------------------------------------------------
// Fused transpose + pool (validated round 3/5).  grid (ci=16, yg=8, b=16) =
// 2048 blocks -> 8 blocks/CU.  Coalesced f4 loads, shfl pool, transpose via
// padded LDS, coalesced 1KB xT stores.
// mode=1: store per-(b,ci,yg) partial sums (no global atomics, no memset).
// mode=0: legacy global atomicAdd into pre-zeroed pooled.
// ---------------------------------------------------------------------------
__global__ void tp_kernel(const float* __restrict__ x,
                          ushort_t* __restrict__ xT,
                          float* __restrict__ pooled,
                          float* __restrict__ part,
                          int mode) {
    const int ci = blockIdx.x, yg = blockIdx.y, b = blockIdx.z;
    const int tid = threadIdx.x;
    const int lane = tid & 63;

    __shared__ ushort_t t2[8 * 1154];        // row stride 1154 us = 577 dw (odd)
    __shared__ float pool_l[16];
    if (tid < 16) pool_l[tid] = 0.f;
    __syncthreads();

    const float* xbase = x + ((size_t)b * C + ci * 16) * (H * W);

    // load + pool + transposed LDS write.  idx = (c, y8, xq)
    #pragma unroll
    for (int j = 0; j < 8; ++j) {
        const int idx = j * 256 + tid;
        const int xq = idx & 15;
        const int y8 = (idx >> 4) & 7;
        const int c  = idx >> 7;             // wave-uniform
        float4 v = *(const float4*)(xbase + ((size_t)c * H + (yg * 8 + y8)) * W + xq * 4);
        float s = (v.x + v.y) + (v.z + v.w);
        s += __shfl_xor(s, 1, 64);
        s += __shfl_xor(s, 2, 64);
        s += __shfl_xor(s, 4, 64);
        s += __shfl_xor(s, 8, 64);           // sum over 16 xq lanes = row sum
        if ((lane & 15) == 0) atomicAdd(&pool_l[c], s);
        ushort_t* d = &t2[y8 * 1154 + (xq * 4) * 18 + c];
        d[0]  = f2bf(v.x);
        d[18] = f2bf(v.y);
        d[36] = f2bf(v.z);
        d[54] = f2bf(v.w);
    }
    __syncthreads();

    // store: 1024 x 16B, e = (y8, col, half); 1KB contiguous per wave
    #pragma unroll
    for (int q = 0; q < 4; ++q) {
        const int e = q * 256 + tid;
        const int y8 = e >> 7, col = (e >> 1) & 63, half = e & 1;
        const ushort_t* s0 = &t2[y8 * 1154 + col * 18 + half * 8];
        uint4 vv;                            // 36B x-stride: 4x aligned u32
        vv.x = *(const unsigned*)(s0 + 0);
        vv.y = *(const unsigned*)(s0 + 2);
        vv.z = *(const unsigned*)(s0 + 4);
        vv.w = *(const unsigned*)(s0 + 6);
        size_t go = (((size_t)(b * 16 + ci) * 64) + (yg * 8 + y8)) * 1024
                  + col * 16 + half * 8;
        *(uint4*)(xT + go) = vv;
    }
    if (mode) {
        if (tid < 16)
            part[(((size_t)(b * 16 + ci)) * 8 + yg) * 16 + tid] = pool_l[tid];
    } else {
        if (tid < 16)
            atomicAdd(&pooled[b * C + ci * 16 + tid], pool_l[tid] * (1.0f / (H * W)));
    }
}

// ---------------------------------------------------------------------------
// Attention.  grid=B, 128 thr.  mode=1: reduce tp's partials; mode=0: read
// pre-accumulated pooled.
// ---------------------------------------------------------------------------
__global__ void attention_kernel(const float* __restrict__ pooled,
                                 const float* __restrict__ part,
                                 const float* __restrict__ w_fc1,
                                 const float* __restrict__ w_fc2,
                                 const float* __restrict__ b_fc2,
                                 float* __restrict__ att,
                                 int mode) {
    const int b = blockIdx.x;
    const int tid = threadIdx.x;
    __shared__ float pool_s[C];
    __shared__ float h_s[HID];
    __shared__ float logit_s[K];

    if (mode) {
        for (int i = tid; i < C; i += blockDim.x) {
            const int ci = i >> 4, cc = i & 15;
            const float* p = part + (((size_t)(b * 16 + ci)) * 8) * 16 + cc;
            float s = 0.f;
            #pragma unroll
            for (int yg = 0; yg < 8; ++yg) s += p[yg * 16];
            pool_s[i] = s * (1.0f / (H * W));
        }
    } else {
        for (int i = tid; i < C; i += blockDim.x) pool_s[i] = pooled[b * C + i];
    }
    __syncthreads();
    for (int j = tid; j < HID; j += blockDim.x) {
        const float* wr = w_fc1 + (size_t)j * C;
        float s = 0.f;
        #pragma unroll 4
        for (int c = 0; c < C; ++c) s += pool_s[c] * wr[c];
        h_s[j] = fmaxf(s, 0.f);
    }
    __syncthreads();
    if (tid < K) {
        const float* wr = w_fc2 + (size_t)tid * HID;
        float s = b_fc2[tid];
        for (int j = 0; j < HID; ++j) s += h_s[j] * wr[j];
        logit_s[tid] = s * (1.0f / TEMP);
    }
    __syncthreads();
    if (tid == 0) {
        float m = fmaxf(fmaxf(logit_s[0], logit_s[1]), fmaxf(logit_s[2], logit_s[3]));
        float e0 = expf(logit_s[0] - m), e1 = expf(logit_s[1] - m);
        float e2 = expf(logit_s[2] - m), e3 = expf(logit_s[3] - m);
        float inv = 1.0f / (e0 + e1 + e2 + e3);
        att[b * K + 0] = e0 * inv; att[b * K + 1] = e1 * inv;
        att[b * K + 2] = e2 * inv; att[b * K + 3] = e3 * inv;
    }
}

// ---------------------------------------------------------------------------
// Weight aggregation v3 (validated round 3/5) -> bf16 in MFMA A-fragment
// lane order.  grid (ci=16, mi=8), 256 thr.  Weight slice staged once to
// LDS (coalesced, 145-dw padded rows); each wave emits (b,t) fragments as
// one fully-coalesced 16B/lane 1KB store.
// ---------------------------------------------------------------------------
__global__ void wagg_kernel(const float* __restrict__ weight,
                            const float* __restrict__ att,
                            ushort_t* __restrict__ wagg_sw) {
    const int ci = blockIdx.x;           // 0..15
    const int mi = blockIdx.y;           // 0..7
    const int tid = threadIdx.x;
    const int lane = tid & 63;
    const int wid  = tid >> 6;

    __shared__ float lds_w[4 * 32 * 145];    // 74,240 B
    __shared__ float att_s[B * K];

    if (tid < B * K) att_s[tid] = att[tid];

    // load: 128 (k,o) segments x 144 contiguous floats (36 f4 each)
    for (int idx = tid; idx < 128 * 36; idx += 256) {
        const int seg = idx / 36;            // k*32 + o
        const int off = idx - seg * 36;
        const int k = seg >> 5, o = seg & 31;
        const float4 v = *(const float4*)(weight
            + ((size_t)(k * O + mi * 32 + o) * C + ci * 16) * 9 + off * 4);
        float* d = &lds_w[seg * 145 + off * 4];
        d[0] = v.x; d[1] = v.y; d[2] = v.z; d[3] = v.w;
    }
    __syncthreads();

    const int o_l = lane & 31;
    const int cc0 = (lane >> 5) * 8;
    for (int task = wid; task < B * 9; task += 4) {
        const int b = task / 9, t = task - b * 9;
        const float a0 = att_s[b * K + 0], a1 = att_s[b * K + 1];
        const float a2 = att_s[b * K + 2], a3 = att_s[b * K + 3];
        union { ushort_t u[8]; uint4 v; } pk;
        #pragma unroll
        for (int j = 0; j < 8; ++j) {
            const int m = (cc0 + j) * 9 + t;
            pk.u[j] = f2bf(a0 * lds_w[(0 * 32 + o_l) * 145 + m]
                         + a1 * lds_w[(1 * 32 + o_l) * 145 + m]
                         + a2 * lds_w[(2 * 32 + o_l) * 145 + m]
                         + a3 * lds_w[(3 * 32 + o_l) * 145 + m]);
        }
        size_t idx = ((((size_t)b * 16 + ci) * 9 + t) * 8 + mi) * 512 + lane * 8;
        *(uint4*)&wagg_sw[idx] = pk.v;
    }
}

// ---------------------------------------------------------------------------
// MFMA conv v6 (resubmit — round-6 bench was an infra failure, no verdict).
// T3+T4 counted-vmcnt double-buffer on the VALIDATED desync structure.
// Keeps: 256 thr / 4 waves, 2 blocks/CU, conflict-free LDS layouts.
// oz split 2->4 (64 o/block, a in {0,1}) so BOTH A and x fit
// double-buffered; 8 global_load_lds per wave per chunk (uniform count,
// OOB rows -> dump).  Main loop: stage(ci+1,buf^1); s_waitcnt vmcnt(8);
// s_barrier; 36 MFMA; s_barrier.  No vmcnt(0) drain except last chunk.
// grid (b=16, yt=16, oz=4) = 1024 blocks.
// ---------------------------------------------------------------------------
__global__ __launch_bounds__(256, 2)
void conv_mfma_kernel(const ushort_t* __restrict__ xT,
                      const ushort_t* __restrict__ wagg_sw,
                      const float* __restrict__ bias,
                      const float* __restrict__ att,
                      float* __restrict__ out) {
    const int b  = blockIdx.x;
    const int yt = blockIdx.y;
    const int oz = blockIdx.z;           // 0..3, 64 outputs each
    const int y0 = yt * 4;

    const int tid  = threadIdx.x;
    const int lane = tid & 63;
    const int wid  = tid >> 6;           // wave -> output row y0+wid
    const int n16  = lane & 31;
    const int khalf = lane >> 5;

    __shared__ __align__(16) ushort_t A_lds[2][18 * 512];   // 2 x 18,432 B
    __shared__ __align__(16) ushort_t x_lds[2][6 * 1056];   // 2 x 12,672 B
    __shared__ __align__(16) ushort_t dump_lds[512];        // OOB/dummy sink
    __shared__ float aggb[64];

    // zero x halos once (both buffers): OOB rows are never staged (they go
    // to dump), col 0/65 of each half-row never written -> stay zero.
    for (int i = tid; i < 2 * 6 * 1056; i += 256) ((ushort_t*)x_lds)[i] = 0;
    __syncthreads();

    // 32 load slots per chunk, slot s = wid + 4k -> exactly 8 per wave:
    //  s in [0,18):  A frag (t = s>>1, a = s&1)
    //  s in [18,30): x (j = s-18, r = j>>1, h = j&1), OOB row -> dump
    //  s in [30,32): dummy (uniform per-wave vmcnt count)
    auto stage = [&](int ci, int buf) {
        const ushort_t* Ab = wagg_sw
            + (((size_t)(b * 16 + ci) * 9) * 8 + oz * 2) * 512 + lane * 8;
        const ushort_t* xb = xT + ((size_t)(b * 16 + ci) * 64) * 1024;
        #pragma unroll
        for (int k = 0; k < 8; ++k) {
            const int s = wid + 4 * k;
            if (s < 18) {
                const int t = s >> 1, a = s & 1;
                gl2lds16(Ab + (size_t)(t * 8 + a) * 512, &A_lds[buf][s * 512]);
            } else if (s < 30) {
                const int j = s - 18, r = j >> 1, h = j & 1;
                const int y = y0 - 1 + r;
                const bool ok = (unsigned)y < (unsigned)H;   // wave-uniform
                gl2lds16(xb + (size_t)(ok ? y : 0) * 1024 + lane * 16 + h * 8,
                         ok ? (void*)&x_lds[buf][r * 1056 + h * 528 + 8]
                            : (void*)&dump_lds[0]);
            } else {
                gl2lds16(Ab, &dump_lds[0]);                  // dummy
            }
        }
    };

    f32x16 acc[2][2];
    #pragma unroll
    for (int a = 0; a < 2; ++a)
        #pragma unroll
        for (int ni = 0; ni < 2; ++ni)
            acc[a][ni] = (f32x16)(0.f);

    stage(0, 0);                         // prologue: chunk 0 -> buf 0

    for (int ci = 0; ci < 16; ++ci) {
        const int cur = ci & 1;
        if (ci < 15) {
            stage(ci + 1, cur ^ 1);      // 8 loads/wave into other buffer
            asm volatile("s_waitcnt vmcnt(8)" ::: "memory"); // chunk ci landed
        } else {
            asm volatile("s_waitcnt vmcnt(0)" ::: "memory"); // peeled drain
        }
        __builtin_amdgcn_s_barrier();    // all waves' chunk-ci staging visible
        asm volatile("" ::: "memory");

        #pragma unroll
        for (int dy = 0; dy < 3; ++dy) {
            const int r = wid + dy;
            #pragma unroll
            for (int dx = 0; dx < 3; ++dx) {
                const int t = dy * 3 + dx;
                bf16x8 bf0 = *(const bf16x8*)&x_lds[cur][r * 1056 + khalf * 528
                              + (n16 + dx) * 8];
                bf16x8 bf1 = *(const bf16x8*)&x_lds[cur][r * 1056 + khalf * 528
                              + (32 + n16 + dx) * 8];
                #pragma unroll
                for (int a = 0; a < 2; ++a) {
                    bf16x8 af = *(const bf16x8*)&A_lds[cur][(t * 2 + a) * 512 + lane * 8];
                    acc[a][0] = __builtin_amdgcn_mfma_f32_32x32x16_bf16(af, bf0, acc[a][0], 0, 0, 0);
                    acc[a][1] = __builtin_amdgcn_mfma_f32_32x32x16_bf16(af, bf1, acc[a][1], 0, 0, 0);
                }
            }
        }
        asm volatile("" ::: "memory");
        __builtin_amdgcn_s_barrier();    // reads of buf[cur] done -> reusable
    }

    // epilogue: aggregated bias, then store
    if (tid < 64) {
        const int o = oz * 64 + tid;
        aggb[tid] = att[b * K + 0] * bias[0 * O + o] + att[b * K + 1] * bias[1 * O + o]
                  + att[b * K + 2] * bias[2 * O + o] + att[b * K + 3] * bias[3 * O + o];
    }
    __syncthreads();

    const int y = y0 + wid;
    #pragma unroll
    for (int a = 0; a < 2; ++a) {
        #pragma unroll
        for (int ni = 0; ni < 2; ++ni) {
            #pragma unroll
            for (int reg = 0; reg < 16; ++reg) {
                const int row = (reg & 3) + 8 * (reg >> 2) + 4 * khalf;
                const int ol  = a * 32 + row;
                out[(((size_t)b * O + oz * 64 + ol) * H + y) * W + ni * 32 + n16]
                    = acc[a][ni][reg] + aggb[ol];
            }
        }
    }
}

// ---------------------------------------------------------------------------
// Fallback fp32 path (round-1, known-correct) if ws too small.
// ---------------------------------------------------------------------------
__global__ void pool_kernel(const float* __restrict__ x, float* __restrict__ pooled) {
    const int bc = blockIdx.x;
    const float4* p4 = (const float4*)(x + (size_t)bc * (H * W));
    const int tid = threadIdx.x;
    float s = 0.f;
    #pragma unroll
    for (int i = 0; i < (H * W / 4) / 256; ++i) {
        float4 v = p4[tid + i * 256];
        s += (v.x + v.y) + (v.z + v.w);
    }
    #pragma unroll
    for (int off = 32; off > 0; off >>= 1) s += __shfl_down(s, off, 64);
    __shared__ float red[4];
    if ((tid & 63) == 0) red[tid >> 6] = s;
    __syncthreads();
    if (tid == 0) pooled[bc] = ((red[0] + red[1]) + (red[2] + red[3])) * (1.0f / (H * W));
}

constexpr int TILE_H = 32;
constexpr int TILE_W = 64;
constexpr int CCF = 4, OT = 8, PX = 8;
constexpr int XS_STRIDE = TILE_W + 3;

__global__ __launch_bounds__(256, 2)
void conv_kernel(const float* __restrict__ x, const float* __restrict__ weight,
                 const float* __restrict__ bias, const float* __restrict__ att,
                 float* __restrict__ out) {
    const int tile_y = blockIdx.x, o0 = blockIdx.y * OT, b = blockIdx.z;
    const int tid = threadIdx.x, tx = tid & 7, ty = tid >> 3, ty0 = tile_y * TILE_H;
    __shared__ __align__(16) float xs[CCF][TILE_H + 2][XS_STRIDE];
    __shared__ __align__(16) float ws_s[OT][CCF][12];
    const float a0 = att[b * K + 0], a1 = att[b * K + 1];
    const float a2 = att[b * K + 2], a3 = att[b * K + 3];
    float acc[OT][PX];
    #pragma unroll
    for (int o = 0; o < OT; ++o)
        #pragma unroll
        for (int p = 0; p < PX; ++p) acc[o][p] = 0.f;
    const float* xb = x + (size_t)b * C * H * W;
    constexpr int X_ELEMS = CCF * (TILE_H + 2) * (TILE_W + 2);
    constexpr int W_ELEMS = OT * CCF * 9;
    for (int c0 = 0; c0 < C; c0 += CCF) {
        __syncthreads();
        for (int idx = tid; idx < X_ELEMS; idx += 256) {
            int cc = idx / ((TILE_H + 2) * (TILE_W + 2));
            int rem = idx - cc * ((TILE_H + 2) * (TILE_W + 2));
            int r = rem / (TILE_W + 2), col = rem - r * (TILE_W + 2);
            int gy = ty0 - 1 + r, gx = col - 1;
            float v = 0.f;
            if ((unsigned)gy < (unsigned)H && (unsigned)gx < (unsigned)W)
                v = xb[((size_t)(c0 + cc) * H + gy) * W + gx];
            xs[cc][r][col] = v;
        }
        for (int idx = tid; idx < W_ELEMS; idx += 256) {
            int o = idx / (CCF * 9), rem = idx - o * (CCF * 9);
            int cc = rem / 9, tap = rem - cc * 9;
            size_t base = ((size_t)(o0 + o) * C + (c0 + cc)) * 9 + tap;
            ws_s[o][cc][tap] = a0 * weight[base] + a1 * weight[(size_t)1 * O * C * 9 + base]
                             + a2 * weight[(size_t)2 * O * C * 9 + base]
                             + a3 * weight[(size_t)3 * O * C * 9 + base];
        }
        __syncthreads();
        #pragma unroll
        for (int cc = 0; cc < CCF; ++cc) {
            float xv[3][10];
            #pragma unroll
            for (int dy = 0; dy < 3; ++dy)
                #pragma unroll
                for (int j = 0; j < 10; ++j) xv[dy][j] = xs[cc][ty + dy][8 * tx + j];
            #pragma unroll
            for (int o = 0; o < OT; ++o) {
                float4 w0 = *(const float4*)&ws_s[o][cc][0];
                float4 w1 = *(const float4*)&ws_s[o][cc][4];
                float w8 = ws_s[o][cc][8];
                #pragma unroll
                for (int p = 0; p < PX; ++p) {
                    float s = acc[o][p];
                    s = fmaf(xv[0][p + 0], w0.x, s); s = fmaf(xv[0][p + 1], w0.y, s);
                    s = fmaf(xv[0][p + 2], w0.z, s); s = fmaf(xv[1][p + 0], w0.w, s);
                    s = fmaf(xv[1][p + 1], w1.x, s); s = fmaf(xv[1][p + 2], w1.y, s);
                    s = fmaf(xv[2][p + 0], w1.z, s); s = fmaf(xv[2][p + 1], w1.w, s);
                    s = fmaf(xv[2][p + 2], w8, s);
                    acc[o][p] = s;
                }
            }
        }
    }
    const int oy = ty0 + ty, ox = 8 * tx;
    #pragma unroll
    for (int o = 0; o < OT; ++o) {
        float ab = a0 * bias[0 * O + o0 + o] + a1 * bias[1 * O + o0 + o]
                 + a2 * bias[2 * O + o0 + o] + a3 * bias[3 * O + o0 + o];
        float4 v0 = make_float4(acc[o][0] + ab, acc[o][1] + ab, acc[o][2] + ab, acc[o][3] + ab);
        float4 v1 = make_float4(acc[o][4] + ab, acc[o][5] + ab, acc[o][6] + ab, acc[o][7] + ab);
        float* op = out + (((size_t)b * O + (o0 + o)) * H + oy) * W + ox;
        *(float4*)(op) = v0; *(float4*)(op + 4) = v1;
    }
}

// ---------------------------------------------------------------------------
extern "C" void kernel_launch(void* const* d_in, const int* in_sizes, int n_in,
                              void* d_out, int out_size, void* d_ws, size_t ws_size,
                              hipStream_t stream) {
    const float* x      = (const float*)d_in[0];
    const float* w_fc1  = (const float*)d_in[1];
    const float* w_fc2  = (const float*)d_in[2];
    const float* b_fc2  = (const float*)d_in[3];
    const float* weight = (const float*)d_in[4];
    const float* bias   = (const float*)d_in[5];
    float* out = (float*)d_out;

    float* pooled = (float*)d_ws;                            // B*C fp32
    float* att    = pooled + B * C;
    ushort_t* wagg_sw = (ushort_t*)((char*)d_ws + 32 * 1024);
    const size_t wagg_bytes = (size_t)B * 16 * 9 * 8 * 512 * 2;      // 18,874,368
    ushort_t* xT = (ushort_t*)((char*)wagg_sw + wagg_bytes);
    const size_t xT_bytes = (size_t)B * 16 * 64 * 64 * 16 * 2;       // 33,554,432
    float* part = (float*)((char*)xT + xT_bytes);            // B*16*8*16 fp32
    const size_t part_bytes = (size_t)B * 16 * 8 * 16 * sizeof(float); // 131,072
    const size_t needed  = 32 * 1024 + wagg_bytes + xT_bytes;
    const size_t needed2 = needed + part_bytes;

    if (ws_size >= needed2) {
        // partial-sum path: no memset, no global atomics
        tp_kernel<<<dim3(16, 8, 16), dim3(256), 0, stream>>>(x, xT, pooled, part, 1);
        attention_kernel<<<dim3(B), dim3(128), 0, stream>>>(pooled, part, w_fc1, w_fc2, b_fc2, att, 1);
        wagg_kernel<<<dim3(16, 8), dim3(256), 0, stream>>>(weight, att, wagg_sw);
        conv_mfma_kernel<<<dim3(B, 16, 4), dim3(256), 0, stream>>>(xT, wagg_sw, bias, att, out);
    } else if (ws_size >= needed) {
        hipMemsetAsync(pooled, 0, B * C * sizeof(float), stream);
        tp_kernel<<<dim3(16, 8, 16), dim3(256), 0, stream>>>(x, xT, pooled, pooled, 0);
        attention_kernel<<<dim3(B), dim3(128), 0, stream>>>(pooled, pooled, w_fc1, w_fc2, b_fc2, att, 0);
        wagg_kernel<<<dim3(16, 8), dim3(256), 0, stream>>>(weight, att, wagg_sw);
        conv_mfma_kernel<<<dim3(B, 16, 4), dim3(256), 0, stream>>>(xT, wagg_sw, bias, att, out);
    } else {
        pool_kernel<<<dim3(B * C), dim3(256), 0, stream>>>(x, pooled);
        attention_kernel<<<dim3(B), dim3(128), 0, stream>>>(pooled, pooled, w_fc1, w_fc2, b_fc2, att, 0);
        conv_kernel<<<dim3(H / TILE_H, O / OT, B), dim3(256), 0, stream>>>(x, weight, bias, att, out);
    }
}

// Round 8
// 219.647 us; speedup vs baseline: 1.0201x; 1.0201x over previous
//
#include <hip/hip_runtime.h>
#include <math.h>

// Problem constants
constexpr int B   = 16;
constexpr int C   = 256;
constexpr int H   = 64;
constexpr int W   = 64;
constexpr int K   = 4;
constexpr int O   = 256;
constexpr int HID = 65;
constexpr float TEMP = 34.0f;

typedef __bf16 bf16x8 __attribute__((ext_vector_type(8)));
typedef float  f32x16 __attribute__((ext_vector_type(16)));
typedef unsigned short ushort_t;

__device__ inline ushort_t f2bf(float f) {
    union { float f; unsigned u; } v; v.f = f;
    unsigned u = v.u;
    u += 0x7FFF + ((u >> 16) & 1);       // RNE
    return (ushort_t)(u >> 16);
}

__device__ inline void gl2lds16(const void* g, void* l) {
    __builtin_amdgcn_global_load_lds(
        (const __attribute__((address_space(1))) unsigned int*)g,
        (__attribute__((address_space(3))) unsigned int*)l, 16, 0, 0);
}

// ---------------------------------------------------------------------------
// Fused transpose + pool (validated rounds 3/5).  grid (ci=16, yg=8, b=16) =
// 2048 blocks -> 8 blocks/CU.  Coalesced f4 loads, shfl pool, transpose via
// padded LDS, coalesced 1KB xT stores.
// mode=1: store per-(b,ci,yg) partial sums (no global atomics, no memset).
// mode=0: legacy global atomicAdd into pre-zeroed pooled.
// ---------------------------------------------------------------------------
__global__ void tp_kernel(const float* __restrict__ x,
                          ushort_t* __restrict__ xT,
                          float* __restrict__ pooled,
                          float* __restrict__ part,
                          int mode) {
    const int ci = blockIdx.x, yg = blockIdx.y, b = blockIdx.z;
    const int tid = threadIdx.x;
    const int lane = tid & 63;

    __shared__ ushort_t t2[8 * 1154];        // row stride 1154 us = 577 dw (odd)
    __shared__ float pool_l[16];
    if (tid < 16) pool_l[tid] = 0.f;
    __syncthreads();

    const float* xbase = x + ((size_t)b * C + ci * 16) * (H * W);

    // load + pool + transposed LDS write.  idx = (c, y8, xq)
    #pragma unroll
    for (int j = 0; j < 8; ++j) {
        const int idx = j * 256 + tid;
        const int xq = idx & 15;
        const int y8 = (idx >> 4) & 7;
        const int c  = idx >> 7;             // wave-uniform
        float4 v = *(const float4*)(xbase + ((size_t)c * H + (yg * 8 + y8)) * W + xq * 4);
        float s = (v.x + v.y) + (v.z + v.w);
        s += __shfl_xor(s, 1, 64);
        s += __shfl_xor(s, 2, 64);
        s += __shfl_xor(s, 4, 64);
        s += __shfl_xor(s, 8, 64);           // sum over 16 xq lanes = row sum
        if ((lane & 15) == 0) atomicAdd(&pool_l[c], s);
        ushort_t* d = &t2[y8 * 1154 + (xq * 4) * 18 + c];
        d[0]  = f2bf(v.x);
        d[18] = f2bf(v.y);
        d[36] = f2bf(v.z);
        d[54] = f2bf(v.w);
    }
    __syncthreads();

    // store: 1024 x 16B, e = (y8, col, half); 1KB contiguous per wave
    #pragma unroll
    for (int q = 0; q < 4; ++q) {
        const int e = q * 256 + tid;
        const int y8 = e >> 7, col = (e >> 1) & 63, half = e & 1;
        const ushort_t* s0 = &t2[y8 * 1154 + col * 18 + half * 8];
        uint4 vv;                            // 36B x-stride: 4x aligned u32
        vv.x = *(const unsigned*)(s0 + 0);
        vv.y = *(const unsigned*)(s0 + 2);
        vv.z = *(const unsigned*)(s0 + 4);
        vv.w = *(const unsigned*)(s0 + 6);
        size_t go = (((size_t)(b * 16 + ci) * 64) + (yg * 8 + y8)) * 1024
                  + col * 16 + half * 8;
        *(uint4*)(xT + go) = vv;
    }
    if (mode) {
        if (tid < 16)
            part[(((size_t)(b * 16 + ci)) * 8 + yg) * 16 + tid] = pool_l[tid];
    } else {
        if (tid < 16)
            atomicAdd(&pooled[b * C + ci * 16 + tid], pool_l[tid] * (1.0f / (H * W)));
    }
}

// ---------------------------------------------------------------------------
// Attention.  grid=B, 128 thr.  mode=1: reduce tp's partials; mode=0: read
// pre-accumulated pooled.
// ---------------------------------------------------------------------------
__global__ void attention_kernel(const float* __restrict__ pooled,
                                 const float* __restrict__ part,
                                 const float* __restrict__ w_fc1,
                                 const float* __restrict__ w_fc2,
                                 const float* __restrict__ b_fc2,
                                 float* __restrict__ att,
                                 int mode) {
    const int b = blockIdx.x;
    const int tid = threadIdx.x;
    __shared__ float pool_s[C];
    __shared__ float h_s[HID];
    __shared__ float logit_s[K];

    if (mode) {
        for (int i = tid; i < C; i += blockDim.x) {
            const int ci = i >> 4, cc = i & 15;
            const float* p = part + (((size_t)(b * 16 + ci)) * 8) * 16 + cc;
            float s = 0.f;
            #pragma unroll
            for (int yg = 0; yg < 8; ++yg) s += p[yg * 16];
            pool_s[i] = s * (1.0f / (H * W));
        }
    } else {
        for (int i = tid; i < C; i += blockDim.x) pool_s[i] = pooled[b * C + i];
    }
    __syncthreads();
    for (int j = tid; j < HID; j += blockDim.x) {
        const float* wr = w_fc1 + (size_t)j * C;
        float s = 0.f;
        #pragma unroll 4
        for (int c = 0; c < C; ++c) s += pool_s[c] * wr[c];
        h_s[j] = fmaxf(s, 0.f);
    }
    __syncthreads();
    if (tid < K) {
        const float* wr = w_fc2 + (size_t)tid * HID;
        float s = b_fc2[tid];
        for (int j = 0; j < HID; ++j) s += h_s[j] * wr[j];
        logit_s[tid] = s * (1.0f / TEMP);
    }
    __syncthreads();
    if (tid == 0) {
        float m = fmaxf(fmaxf(logit_s[0], logit_s[1]), fmaxf(logit_s[2], logit_s[3]));
        float e0 = expf(logit_s[0] - m), e1 = expf(logit_s[1] - m);
        float e2 = expf(logit_s[2] - m), e3 = expf(logit_s[3] - m);
        float inv = 1.0f / (e0 + e1 + e2 + e3);
        att[b * K + 0] = e0 * inv; att[b * K + 1] = e1 * inv;
        att[b * K + 2] = e2 * inv; att[b * K + 3] = e3 * inv;
    }
}

// ---------------------------------------------------------------------------
// Weight aggregation v3 (validated rounds 3/5) -> bf16 in MFMA A-fragment
// lane order.  grid (ci=16, mi=8), 256 thr.  Weight slice staged once to
// LDS (coalesced, 145-dw padded rows); each wave emits (b,t) fragments as
// one fully-coalesced 16B/lane 1KB store.
// ---------------------------------------------------------------------------
__global__ void wagg_kernel(const float* __restrict__ weight,
                            const float* __restrict__ att,
                            ushort_t* __restrict__ wagg_sw) {
    const int ci = blockIdx.x;           // 0..15
    const int mi = blockIdx.y;           // 0..7
    const int tid = threadIdx.x;
    const int lane = tid & 63;
    const int wid  = tid >> 6;

    __shared__ float lds_w[4 * 32 * 145];    // 74,240 B
    __shared__ float att_s[B * K];

    if (tid < B * K) att_s[tid] = att[tid];

    // load: 128 (k,o) segments x 144 contiguous floats (36 f4 each)
    for (int idx = tid; idx < 128 * 36; idx += 256) {
        const int seg = idx / 36;            // k*32 + o
        const int off = idx - seg * 36;
        const int k = seg >> 5, o = seg & 31;
        const float4 v = *(const float4*)(weight
            + ((size_t)(k * O + mi * 32 + o) * C + ci * 16) * 9 + off * 4);
        float* d = &lds_w[seg * 145 + off * 4];
        d[0] = v.x; d[1] = v.y; d[2] = v.z; d[3] = v.w;
    }
    __syncthreads();

    const int o_l = lane & 31;
    const int cc0 = (lane >> 5) * 8;
    for (int task = wid; task < B * 9; task += 4) {
        const int b = task / 9, t = task - b * 9;
        const float a0 = att_s[b * K + 0], a1 = att_s[b * K + 1];
        const float a2 = att_s[b * K + 2], a3 = att_s[b * K + 3];
        union { ushort_t u[8]; uint4 v; } pk;
        #pragma unroll
        for (int j = 0; j < 8; ++j) {
            const int m = (cc0 + j) * 9 + t;
            pk.u[j] = f2bf(a0 * lds_w[(0 * 32 + o_l) * 145 + m]
                         + a1 * lds_w[(1 * 32 + o_l) * 145 + m]
                         + a2 * lds_w[(2 * 32 + o_l) * 145 + m]
                         + a3 * lds_w[(3 * 32 + o_l) * 145 + m]);
        }
        size_t idx = ((((size_t)b * 16 + ci) * 9 + t) * 8 + mi) * 512 + lane * 8;
        *(uint4*)&wagg_sw[idx] = pk.v;
    }
}

// ---------------------------------------------------------------------------
// MFMA conv: EXACT round-2/3/5 version (validated best: 70.2-72.7us,
// MfmaUtil 46-48%, SQ_LDS_BANK_CONFLICT = 0, FETCH 25.9MB).  32x32x16,
// wave tile 4m x 2n, 256 thr, 2 blocks/CU desync, grid (b=16, yt=16, oz=2).
// Four pipelining/restaging variants (rounds 1, 4, 7) all regressed:
// cross-block desync already absorbs the barrier drain at this occupancy.
// ---------------------------------------------------------------------------
__global__ __launch_bounds__(256, 2)
void conv_mfma_kernel(const ushort_t* __restrict__ xT,
                      const ushort_t* __restrict__ wagg_sw,
                      const float* __restrict__ bias,
                      const float* __restrict__ att,
                      float* __restrict__ out) {
    const int b  = blockIdx.x;
    const int yt = blockIdx.y;
    const int oz = blockIdx.z;
    const int y0 = yt * 4;

    const int tid  = threadIdx.x;
    const int lane = tid & 63;
    const int wid  = tid >> 6;           // wave -> output row y0+wid
    const int n16  = lane & 31;
    const int khalf = lane >> 5;

    __shared__ __align__(16) ushort_t A_lds[9 * 4 * 512];   // 36,864 B
    __shared__ __align__(16) ushort_t x_lds[6 * 1056];      // [r][kh2][col66][cc8] 12,672 B

    // zero x halos (OOB rows + col 0/65 of each half never overwritten)
    for (int i = tid; i < 6 * 1056; i += 256) x_lds[i] = 0;

    f32x16 acc[4][2];
    #pragma unroll
    for (int a = 0; a < 4; ++a)
        #pragma unroll
        for (int ni = 0; ni < 2; ++ni)
            acc[a][ni] = (f32x16)(0.f);

    for (int ci = 0; ci < 16; ++ci) {
        __syncthreads();   // previous chunk's LDS reads complete

        // stage A: 36 x 1KB
        for (int i = wid; i < 36; i += 4) {
            const int t = i >> 2, a = i & 3;
            const ushort_t* g = wagg_sw
                + ((((size_t)b * 16 + ci) * 9 + t) * 8 + (oz * 4 + a)) * 512 + lane * 8;
            gl2lds16(g, &A_lds[(t * 4 + a) * 512]);
        }
        // stage x: 6 rows x 2 halves x 1KB; per-lane global pre-swizzle
        for (int r = wid; r < 6; r += 4) {
            const int y = y0 - 1 + r;
            if ((unsigned)y < (unsigned)H) {
                const ushort_t* gr = xT + (((size_t)(b * 16 + ci) * 64 + y) * 1024);
                #pragma unroll
                for (int h = 0; h < 2; ++h)
                    gl2lds16(gr + lane * 16 + h * 8,
                             &x_lds[r * 1056 + h * 528 + 8]);
            }
        }

        __syncthreads();   // drain vmcnt -> staged data visible

        #pragma unroll
        for (int dy = 0; dy < 3; ++dy) {
            const int r = wid + dy;
            #pragma unroll
            for (int dx = 0; dx < 3; ++dx) {
                const int t = dy * 3 + dx;
                bf16x8 bf[2];
                #pragma unroll
                for (int ni = 0; ni < 2; ++ni)
                    bf[ni] = *(const bf16x8*)&x_lds[r * 1056 + khalf * 528
                              + (ni * 32 + n16 + dx) * 8];
                #pragma unroll
                for (int a = 0; a < 4; ++a) {
                    bf16x8 af = *(const bf16x8*)&A_lds[(t * 4 + a) * 512 + lane * 8];
                    acc[a][0] = __builtin_amdgcn_mfma_f32_32x32x16_bf16(af, bf[0], acc[a][0], 0, 0, 0);
                    acc[a][1] = __builtin_amdgcn_mfma_f32_32x32x16_bf16(af, bf[1], acc[a][1], 0, 0, 0);
                }
            }
        }
    }

    // epilogue: aggregated bias via LDS (reuse A_lds), then store
    __syncthreads();
    float* aggb = (float*)A_lds;
    if (tid < 128) {
        const int o = oz * 128 + tid;
        aggb[tid] = att[b * K + 0] * bias[0 * O + o] + att[b * K + 1] * bias[1 * O + o]
                  + att[b * K + 2] * bias[2 * O + o] + att[b * K + 3] * bias[3 * O + o];
    }
    __syncthreads();

    const int y = y0 + wid;
    #pragma unroll
    for (int a = 0; a < 4; ++a) {
        #pragma unroll
        for (int ni = 0; ni < 2; ++ni) {
            #pragma unroll
            for (int reg = 0; reg < 16; ++reg) {
                const int row = (reg & 3) + 8 * (reg >> 2) + 4 * khalf;
                const int ol  = a * 32 + row;
                out[(((size_t)b * O + oz * 128 + ol) * H + y) * W + ni * 32 + n16]
                    = acc[a][ni][reg] + aggb[ol];
            }
        }
    }
}

// ---------------------------------------------------------------------------
// Fallback fp32 path (round-1, known-correct) if ws too small.
// ---------------------------------------------------------------------------
__global__ void pool_kernel(const float* __restrict__ x, float* __restrict__ pooled) {
    const int bc = blockIdx.x;
    const float4* p4 = (const float4*)(x + (size_t)bc * (H * W));
    const int tid = threadIdx.x;
    float s = 0.f;
    #pragma unroll
    for (int i = 0; i < (H * W / 4) / 256; ++i) {
        float4 v = p4[tid + i * 256];
        s += (v.x + v.y) + (v.z + v.w);
    }
    #pragma unroll
    for (int off = 32; off > 0; off >>= 1) s += __shfl_down(s, off, 64);
    __shared__ float red[4];
    if ((tid & 63) == 0) red[tid >> 6] = s;
    __syncthreads();
    if (tid == 0) pooled[bc] = ((red[0] + red[1]) + (red[2] + red[3])) * (1.0f / (H * W));
}

constexpr int TILE_H = 32;
constexpr int TILE_W = 64;
constexpr int CCF = 4, OT = 8, PX = 8;
constexpr int XS_STRIDE = TILE_W + 3;

__global__ __launch_bounds__(256, 2)
void conv_kernel(const float* __restrict__ x, const float* __restrict__ weight,
                 const float* __restrict__ bias, const float* __restrict__ att,
                 float* __restrict__ out) {
    const int tile_y = blockIdx.x, o0 = blockIdx.y * OT, b = blockIdx.z;
    const int tid = threadIdx.x, tx = tid & 7, ty = tid >> 3, ty0 = tile_y * TILE_H;
    __shared__ __align__(16) float xs[CCF][TILE_H + 2][XS_STRIDE];
    __shared__ __align__(16) float ws_s[OT][CCF][12];
    const float a0 = att[b * K + 0], a1 = att[b * K + 1];
    const float a2 = att[b * K + 2], a3 = att[b * K + 3];
    float acc[OT][PX];
    #pragma unroll
    for (int o = 0; o < OT; ++o)
        #pragma unroll
        for (int p = 0; p < PX; ++p) acc[o][p] = 0.f;
    const float* xb = x + (size_t)b * C * H * W;
    constexpr int X_ELEMS = CCF * (TILE_H + 2) * (TILE_W + 2);
    constexpr int W_ELEMS = OT * CCF * 9;
    for (int c0 = 0; c0 < C; c0 += CCF) {
        __syncthreads();
        for (int idx = tid; idx < X_ELEMS; idx += 256) {
            int cc = idx / ((TILE_H + 2) * (TILE_W + 2));
            int rem = idx - cc * ((TILE_H + 2) * (TILE_W + 2));
            int r = rem / (TILE_W + 2), col = rem - r * (TILE_W + 2);
            int gy = ty0 - 1 + r, gx = col - 1;
            float v = 0.f;
            if ((unsigned)gy < (unsigned)H && (unsigned)gx < (unsigned)W)
                v = xb[((size_t)(c0 + cc) * H + gy) * W + gx];
            xs[cc][r][col] = v;
        }
        for (int idx = tid; idx < W_ELEMS; idx += 256) {
            int o = idx / (CCF * 9), rem = idx - o * (CCF * 9);
            int cc = rem / 9, tap = rem - cc * 9;
            size_t base = ((size_t)(o0 + o) * C + (c0 + cc)) * 9 + tap;
            ws_s[o][cc][tap] = a0 * weight[base] + a1 * weight[(size_t)1 * O * C * 9 + base]
                             + a2 * weight[(size_t)2 * O * C * 9 + base]
                             + a3 * weight[(size_t)3 * O * C * 9 + base];
        }
        __syncthreads();
        #pragma unroll
        for (int cc = 0; cc < CCF; ++cc) {
            float xv[3][10];
            #pragma unroll
            for (int dy = 0; dy < 3; ++dy)
                #pragma unroll
                for (int j = 0; j < 10; ++j) xv[dy][j] = xs[cc][ty + dy][8 * tx + j];
            #pragma unroll
            for (int o = 0; o < OT; ++o) {
                float4 w0 = *(const float4*)&ws_s[o][cc][0];
                float4 w1 = *(const float4*)&ws_s[o][cc][4];
                float w8 = ws_s[o][cc][8];
                #pragma unroll
                for (int p = 0; p < PX; ++p) {
                    float s = acc[o][p];
                    s = fmaf(xv[0][p + 0], w0.x, s); s = fmaf(xv[0][p + 1], w0.y, s);
                    s = fmaf(xv[0][p + 2], w0.z, s); s = fmaf(xv[1][p + 0], w0.w, s);
                    s = fmaf(xv[1][p + 1], w1.x, s); s = fmaf(xv[1][p + 2], w1.y, s);
                    s = fmaf(xv[2][p + 0], w1.z, s); s = fmaf(xv[2][p + 1], w1.w, s);
                    s = fmaf(xv[2][p + 2], w8, s);
                    acc[o][p] = s;
                }
            }
        }
    }
    const int oy = ty0 + ty, ox = 8 * tx;
    #pragma unroll
    for (int o = 0; o < OT; ++o) {
        float ab = a0 * bias[0 * O + o0 + o] + a1 * bias[1 * O + o0 + o]
                 + a2 * bias[2 * O + o0 + o] + a3 * bias[3 * O + o0 + o];
        float4 v0 = make_float4(acc[o][0] + ab, acc[o][1] + ab, acc[o][2] + ab, acc[o][3] + ab);
        float4 v1 = make_float4(acc[o][4] + ab, acc[o][5] + ab, acc[o][6] + ab, acc[o][7] + ab);
        float* op = out + (((size_t)b * O + (o0 + o)) * H + oy) * W + ox;
        *(float4*)(op) = v0; *(float4*)(op + 4) = v1;
    }
}

// ---------------------------------------------------------------------------
extern "C" void kernel_launch(void* const* d_in, const int* in_sizes, int n_in,
                              void* d_out, int out_size, void* d_ws, size_t ws_size,
                              hipStream_t stream) {
    const float* x      = (const float*)d_in[0];
    const float* w_fc1  = (const float*)d_in[1];
    const float* w_fc2  = (const float*)d_in[2];
    const float* b_fc2  = (const float*)d_in[3];
    const float* weight = (const float*)d_in[4];
    const float* bias   = (const float*)d_in[5];
    float* out = (float*)d_out;

    float* pooled = (float*)d_ws;                            // B*C fp32
    float* att    = pooled + B * C;
    ushort_t* wagg_sw = (ushort_t*)((char*)d_ws + 32 * 1024);
    const size_t wagg_bytes = (size_t)B * 16 * 9 * 8 * 512 * 2;      // 18,874,368
    ushort_t* xT = (ushort_t*)((char*)wagg_sw + wagg_bytes);
    const size_t xT_bytes = (size_t)B * 16 * 64 * 64 * 16 * 2;       // 33,554,432
    float* part = (float*)((char*)xT + xT_bytes);            // B*16*8*16 fp32
    const size_t part_bytes = (size_t)B * 16 * 8 * 16 * sizeof(float); // 131,072
    const size_t needed  = 32 * 1024 + wagg_bytes + xT_bytes;
    const size_t needed2 = needed + part_bytes;

    if (ws_size >= needed2) {
        // partial-sum path: no memset, no global atomics
        tp_kernel<<<dim3(16, 8, 16), dim3(256), 0, stream>>>(x, xT, pooled, part, 1);
        attention_kernel<<<dim3(B), dim3(128), 0, stream>>>(pooled, part, w_fc1, w_fc2, b_fc2, att, 1);
        wagg_kernel<<<dim3(16, 8), dim3(256), 0, stream>>>(weight, att, wagg_sw);
        conv_mfma_kernel<<<dim3(B, 16, 2), dim3(256), 0, stream>>>(xT, wagg_sw, bias, att, out);
    } else if (ws_size >= needed) {
        hipMemsetAsync(pooled, 0, B * C * sizeof(float), stream);
        tp_kernel<<<dim3(16, 8, 16), dim3(256), 0, stream>>>(x, xT, pooled, pooled, 0);
        attention_kernel<<<dim3(B), dim3(128), 0, stream>>>(pooled, pooled, w_fc1, w_fc2, b_fc2, att, 0);
        wagg_kernel<<<dim3(16, 8), dim3(256), 0, stream>>>(weight, att, wagg_sw);
        conv_mfma_kernel<<<dim3(B, 16, 2), dim3(256), 0, stream>>>(xT, wagg_sw, bias, att, out);
    } else {
        pool_kernel<<<dim3(B * C), dim3(256), 0, stream>>>(x, pooled);
        attention_kernel<<<dim3(B), dim3(128), 0, stream>>>(pooled, pooled, w_fc1, w_fc2, b_fc2, att, 0);
        conv_kernel<<<dim3(H / TILE_H, O / OT, B), dim3(256), 0, stream>>>(x, weight, bias, att, out);
    }
}